// Round 1
// baseline (440.646 us; speedup 1.0000x reference)
//
#include <hip/hip_runtime.h>

typedef __attribute__((ext_vector_type(8))) short bf16x8;   // 8 bf16 in 4 VGPRs
typedef __attribute__((ext_vector_type(4))) float f32x4;

#define HW 4096
#define CDIM 256

__device__ __forceinline__ unsigned short f2bf(float f) {
    union { float f; unsigned u; } v; v.f = f;
    unsigned r = v.u + 0x7fffu + ((v.u >> 16) & 1u);   // RTNE
    return (unsigned short)(r >> 16);
}

// ---------------------------------------------------------------------------
// Kernel 1: projections. For each (b, inp): Out[o][n] = sum_ci W[o][ci]*X[ci][n]+b
// o in [0,448): [0,64)=q -> Q[b][n][2o+inp] (interleaved), [64,192)=k -> K[b,inp][m=n][c],
// [192,448)=v -> V[b,inp][c][m=n] (natural D layout). All bf16.
// Block: (b, inp, ntile of 64 n). 4 waves x 7 osubs x 4 nsubs, K=256 in 8 steps.
// ---------------------------------------------------------------------------
__global__ __launch_bounds__(256) void proj_kernel(
    const float* __restrict__ in1, const float* __restrict__ in2,
    const float* __restrict__ Wq1, const float* __restrict__ bq1,
    const float* __restrict__ Wk1, const float* __restrict__ bk1,
    const float* __restrict__ Wv1, const float* __restrict__ bv1,
    const float* __restrict__ Wq2, const float* __restrict__ bq2,
    const float* __restrict__ Wk2, const float* __restrict__ bk2,
    const float* __restrict__ Wv2, const float* __restrict__ bv2,
    unsigned short* __restrict__ Qg, unsigned short* __restrict__ Kg,
    unsigned short* __restrict__ Vg)
{
    const int bid   = blockIdx.x;
    const int ntile = bid & 63;
    const int inp   = (bid >> 6) & 1;
    const int b     = bid >> 7;

    const float* X  = (inp ? in2 : in1) + (size_t)b * CDIM * HW;
    const float* Wq = inp ? Wq2 : Wq1;  const float* bq = inp ? bq2 : bq1;
    const float* Wk = inp ? Wk2 : Wk1;  const float* bk = inp ? bk2 : bk1;
    const float* Wv = inp ? Wv2 : Wv1;  const float* bv = inp ? bv2 : bv1;

    const int lane = threadIdx.x & 63;
    const int w    = threadIdx.x >> 6;
    const int l15  = lane & 15, quad = lane >> 4;
    const int n0   = ntile * 64;

    f32x4 acc[7][4];
#pragma unroll
    for (int i = 0; i < 7; ++i)
#pragma unroll
        for (int j = 0; j < 4; ++j) acc[i][j] = (f32x4){0.f, 0.f, 0.f, 0.f};

    for (int kk = 0; kk < 8; ++kk) {
        const int ci0 = kk * 32 + quad * 8;
        bf16x8 bfr[4];
#pragma unroll
        for (int ns = 0; ns < 4; ++ns) {
            const int n = n0 + ns * 16 + l15;
            const float* xp = X + (size_t)ci0 * HW + n;
#pragma unroll
            for (int j = 0; j < 8; ++j) bfr[ns][j] = (short)f2bf(xp[(size_t)j * HW]);
        }
#pragma unroll
        for (int os = 0; os < 7; ++os) {
            const int osub = w * 7 + os;
            const int o    = osub * 16 + l15;      // A-frag row = lane&15
            const float* wrow;
            if (osub < 4)       wrow = Wq + (size_t)o * CDIM;
            else if (osub < 12) wrow = Wk + (size_t)(o - 64) * CDIM;
            else                wrow = Wv + (size_t)(o - 192) * CDIM;
            bf16x8 afr;
#pragma unroll
            for (int j = 0; j < 8; ++j) afr[j] = (short)f2bf(wrow[ci0 + j]);
#pragma unroll
            for (int ns = 0; ns < 4; ++ns)
                acc[os][ns] = __builtin_amdgcn_mfma_f32_16x16x32_bf16(afr, bfr[ns], acc[os][ns], 0, 0, 0);
        }
    }

    const size_t qbase = (size_t)b * HW * 128;
    const size_t kbase = (size_t)(b * 2 + inp) * HW * 128;
    const size_t vbase = (size_t)(b * 2 + inp) * (size_t)CDIM * HW;
#pragma unroll
    for (int os = 0; os < 7; ++os) {
        const int osub = w * 7 + os;
#pragma unroll
        for (int ns = 0; ns < 4; ++ns) {
            const int n = n0 + ns * 16 + l15;      // D col = lane&15
            f32x4 d = acc[os][ns];
#pragma unroll
            for (int r = 0; r < 4; ++r) {
                const int o = osub * 16 + quad * 4 + r;   // D row = quad*4+reg
                if (osub < 4) {
                    Qg[qbase + (size_t)n * 128 + 2 * o + inp] = f2bf(d[r] + bq[o]);
                } else if (osub < 12) {
                    const int c = o - 64;
                    Kg[kbase + (size_t)n * 128 + c] = f2bf(d[r] + bk[c]);
                } else {
                    const int c = o - 192;
                    Vg[vbase + (size_t)c * HW + n] = f2bf(d[r] + bv[c]);
                }
            }
        }
    }
}

// ---------------------------------------------------------------------------
// Kernel 2: streaming attention (no max-subtraction; scores are O(6) max).
// Block = (b, att, qtile of 64 rows). 4 waves: (nhalf = w>>1) x (half2 = w&1),
// half2 doubles as m-half for S and c-half for PV.
// ---------------------------------------------------------------------------
__global__ __launch_bounds__(256) void attn_kernel(
    const unsigned short* __restrict__ Qg, const unsigned short* __restrict__ Kg,
    const unsigned short* __restrict__ Vg,
    const float* __restrict__ in1, const float* __restrict__ in2,
    const float* __restrict__ gamma_p, float* __restrict__ out)
{
    __shared__ unsigned short ktile[64 * 136];   // [m][c] pad 128->136
    __shared__ unsigned short vtile[256 * 72];   // [c][m] pad 64->72
    __shared__ unsigned short pbuf[64 * 72];     // [n][m] pad 64->72
    __shared__ float lbuf[2][64];

    const int bid = blockIdx.x;
    const int qt  = bid & 63, att = (bid >> 6) & 1, b = bid >> 7;
    const int n0  = qt * 64;
    const int tid = threadIdx.x;
    const int lane = tid & 63, w = tid >> 6;
    const int l15 = lane & 15, quad = lane >> 4;
    const int nhalf = w >> 1, half2 = w & 1;

    const unsigned short* Qb = Qg + (size_t)b * HW * 128;
    const unsigned short* Kb = Kg + (size_t)(b * 2 + att) * HW * 128;
    const unsigned short* Vb = Vg + (size_t)(b * 2 + att) * (size_t)CDIM * HW;

    // Preload Q A-frags: A[n=lane&15][k=quad*8+j], kk steps of 32 over c=128
    bf16x8 aQ[2][4];
#pragma unroll
    for (int ns = 0; ns < 2; ++ns) {
        const int n = n0 + nhalf * 32 + ns * 16 + l15;
#pragma unroll
        for (int kk = 0; kk < 4; ++kk)
            aQ[ns][kk] = *(const bf16x8*)(Qb + (size_t)n * 128 + kk * 32 + quad * 8);
    }

    f32x4 O[2][8];
#pragma unroll
    for (int i = 0; i < 2; ++i)
#pragma unroll
        for (int j = 0; j < 8; ++j) O[i][j] = (f32x4){0.f, 0.f, 0.f, 0.f};
    f32x4 lsum[2] = { (f32x4){0.f,0.f,0.f,0.f}, (f32x4){0.f,0.f,0.f,0.f} };

    for (int mt = 0; mt < 64; ++mt) {
        const int m0 = mt * 64;
        __syncthreads();                       // prior tile's LDS reads done
        // stage K tile [64m][128c] and V tile [256c][64m], b128 all the way
#pragma unroll
        for (int i = 0; i < 4; ++i) {
            const int idx = tid + i * 256;
            const int ml = idx >> 4, part = idx & 15;
            *(bf16x8*)&ktile[ml * 136 + part * 8] =
                *(const bf16x8*)(Kb + (size_t)(m0 + ml) * 128 + part * 8);
        }
#pragma unroll
        for (int i = 0; i < 8; ++i) {
            const int idx = tid + i * 256;
            const int c = idx >> 3, part = idx & 7;
            *(bf16x8*)&vtile[c * 72 + part * 8] =
                *(const bf16x8*)(Vb + (size_t)c * HW + m0 + part * 8);
        }
        __syncthreads();

        // S quarter [32n x 32m]: this wave's (nhalf, mhalf=half2)
        f32x4 s[2][2];
#pragma unroll
        for (int i = 0; i < 2; ++i)
#pragma unroll
            for (int j = 0; j < 2; ++j) s[i][j] = (f32x4){0.f, 0.f, 0.f, 0.f};
#pragma unroll
        for (int ms = 0; ms < 2; ++ms) {
            const int mloc = half2 * 32 + ms * 16 + l15;    // B col = lane&15
#pragma unroll
            for (int kk = 0; kk < 4; ++kk) {
                bf16x8 bK = *(const bf16x8*)&ktile[mloc * 136 + kk * 32 + quad * 8];
#pragma unroll
                for (int ns = 0; ns < 2; ++ns)
                    s[ns][ms] = __builtin_amdgcn_mfma_f32_16x16x32_bf16(aQ[ns][kk], bK, s[ns][ms], 0, 0, 0);
            }
        }
        // exp (no max-sub), accumulate l, write P quarter to pbuf
#pragma unroll
        for (int ns = 0; ns < 2; ++ns)
#pragma unroll
            for (int ms = 0; ms < 2; ++ms) {
                f32x4 p;
#pragma unroll
                for (int r = 0; r < 4; ++r) p[r] = __expf(s[ns][ms][r]);
                lsum[ns] += p;
#pragma unroll
                for (int r = 0; r < 4; ++r) {
                    const int nl = nhalf * 32 + ns * 16 + quad * 4 + r;  // D row
                    const int ml = half2 * 32 + ms * 16 + l15;           // D col
                    pbuf[nl * 72 + ml] = f2bf(p[r]);
                }
            }
        __syncthreads();

        // PV: O[n][c] += P[n][m] * Vt[m][c]; this wave: nhalf rows, chalf=half2 cols
        bf16x8 aP[2][2];
#pragma unroll
        for (int ns = 0; ns < 2; ++ns)
#pragma unroll
            for (int k2 = 0; k2 < 2; ++k2)
                aP[ns][k2] = *(const bf16x8*)&pbuf[(nhalf * 32 + ns * 16 + l15) * 72 + k2 * 32 + quad * 8];
#pragma unroll
        for (int cs = 0; cs < 8; ++cs) {
            const int c = half2 * 128 + cs * 16 + l15;
#pragma unroll
            for (int k2 = 0; k2 < 2; ++k2) {
                bf16x8 bV = *(const bf16x8*)&vtile[c * 72 + k2 * 32 + quad * 8];
#pragma unroll
                for (int ns = 0; ns < 2; ++ns)
                    O[ns][cs] = __builtin_amdgcn_mfma_f32_16x16x32_bf16(aP[ns][k2], bV, O[ns][cs], 0, 0, 0);
            }
        }
    }

    // reduce l across the 16 lanes of each quad, combine m-halves via LDS
#pragma unroll
    for (int ns = 0; ns < 2; ++ns)
#pragma unroll
        for (int off = 1; off < 16; off <<= 1)
#pragma unroll
            for (int r = 0; r < 4; ++r) lsum[ns][r] += __shfl_xor(lsum[ns][r], off, 64);
    if (l15 == 0) {
#pragma unroll
        for (int ns = 0; ns < 2; ++ns) {
            const int nl = nhalf * 32 + ns * 16 + quad * 4;
            *(f32x4*)&lbuf[half2][nl] = lsum[ns];
        }
    }
    __syncthreads();

    const float* inp  = (att ? in2 : in1) + (size_t)b * CDIM * HW;
    float*       outp = out + (size_t)att * 2 * CDIM * HW + (size_t)b * CDIM * HW;
    const float  g    = *gamma_p;
#pragma unroll
    for (int ns = 0; ns < 2; ++ns) {
        const int nlb = nhalf * 32 + ns * 16 + quad * 4;
        f32x4 l0 = *(f32x4*)&lbuf[0][nlb];
        f32x4 l1 = *(f32x4*)&lbuf[1][nlb];
        f32x4 linv;
#pragma unroll
        for (int r = 0; r < 4; ++r) linv[r] = 1.0f / (l0[r] + l1[r]);
#pragma unroll
        for (int cs = 0; cs < 8; ++cs) {
            const int c = half2 * 128 + cs * 16 + l15;
            const size_t base = (size_t)c * HW + n0 + nlb;
            f32x4 iv = *(const f32x4*)(inp + base);
            f32x4 ov;
#pragma unroll
            for (int r = 0; r < 4; ++r) ov[r] = g * O[ns][cs][r] * linv[r] + iv[r];
            *(f32x4*)(outp + base) = ov;
        }
    }
}

extern "C" void kernel_launch(void* const* d_in, const int* in_sizes, int n_in,
                              void* d_out, int out_size, void* d_ws, size_t ws_size,
                              hipStream_t stream) {
    const float* in1 = (const float*)d_in[0];
    const float* in2 = (const float*)d_in[1];
    const float* Wq1 = (const float*)d_in[2];  const float* bq1 = (const float*)d_in[3];
    const float* Wk1 = (const float*)d_in[4];  const float* bk1 = (const float*)d_in[5];
    const float* Wv1 = (const float*)d_in[6];  const float* bv1 = (const float*)d_in[7];
    const float* Wq2 = (const float*)d_in[8];  const float* bq2 = (const float*)d_in[9];
    const float* Wk2 = (const float*)d_in[10]; const float* bk2 = (const float*)d_in[11];
    const float* Wv2 = (const float*)d_in[12]; const float* bv2 = (const float*)d_in[13];
    const float* gamma = (const float*)d_in[14];

    unsigned short* Qg = (unsigned short*)d_ws;                 // [2][4096][128]
    unsigned short* Kg = Qg + (size_t)2 * HW * 128;             // [2*2][4096 m][128 c]
    unsigned short* Vg = Kg + (size_t)4 * HW * 128;             // [2*2][256 c][4096 m]

    proj_kernel<<<256, 256, 0, stream>>>(in1, in2, Wq1, bq1, Wk1, bk1, Wv1, bv1,
                                         Wq2, bq2, Wk2, bk2, Wv2, bv2, Qg, Kg, Vg);
    attn_kernel<<<256, 256, 0, stream>>>(Qg, Kg, Vg, in1, in2, gamma, (float*)d_out);
}

// Round 2
// 249.588 us; speedup vs baseline: 1.7655x; 1.7655x over previous
//
#include <hip/hip_runtime.h>

typedef __attribute__((ext_vector_type(8))) short bf16x8;   // 8 bf16 in 4 VGPRs
typedef __attribute__((ext_vector_type(4))) float f32x4;

#define HW 4096
#define CDIM 256

__device__ __forceinline__ unsigned short f2bf(float f) {   // RTNE
    union { float f; unsigned u; } v; v.f = f;
    unsigned r = v.u + 0x7fffu + ((v.u >> 16) & 1u);
    return (unsigned short)(r >> 16);
}

// pack bf16(lo) into low16, bf16(hi) into high16 — TRUNCATION via v_perm_b32
__device__ __forceinline__ unsigned pk2(float hi, float lo) {
    union { float f; unsigned u; } a, b; a.f = hi; b.f = lo;
    return __builtin_amdgcn_perm(a.u, b.u, 0x07060302u);
}

// async global->LDS, 16B per lane; LDS dest = base + lane*16 (wave-uniform base)
__device__ __forceinline__ void gl_lds16(const unsigned short* g, unsigned short* l) {
    __builtin_amdgcn_global_load_lds(
        (const __attribute__((address_space(1))) unsigned int*)(unsigned long long)g,
        (__attribute__((address_space(3))) unsigned int*)(unsigned int)(unsigned long long)l,
        16, 0, 0);
}

// ---------------------------------------------------------------------------
// Kernel 1: projections. grid 512: ntile(128 of 32 n) x inp(2) x b(2).
// Out[o][n] = sum_ci W[o][ci]*X[ci][n] + bias. 4 waves x 7 osubs x 2 nsubs.
// o: [0,64)=q -> Q[b][n][2o+inp], [64,192)=k -> K[b,inp][m][c],
// [192,448)=v -> V[b,inp][c][m]. bf16 outputs in ws.
// ---------------------------------------------------------------------------
__global__ __launch_bounds__(256) void proj_kernel(
    const float* __restrict__ in1, const float* __restrict__ in2,
    const float* __restrict__ Wq1, const float* __restrict__ bq1,
    const float* __restrict__ Wk1, const float* __restrict__ bk1,
    const float* __restrict__ Wv1, const float* __restrict__ bv1,
    const float* __restrict__ Wq2, const float* __restrict__ bq2,
    const float* __restrict__ Wk2, const float* __restrict__ bk2,
    const float* __restrict__ Wv2, const float* __restrict__ bv2,
    unsigned short* __restrict__ Qg, unsigned short* __restrict__ Kg,
    unsigned short* __restrict__ Vg)
{
    const int bid   = blockIdx.x;
    const int ntile = bid & 127;
    const int inp   = (bid >> 7) & 1;
    const int b     = bid >> 8;

    const float* X  = (inp ? in2 : in1) + (size_t)b * CDIM * HW;
    const float* Wq = inp ? Wq2 : Wq1;  const float* bq = inp ? bq2 : bq1;
    const float* Wk = inp ? Wk2 : Wk1;  const float* bk = inp ? bk2 : bk1;
    const float* Wv = inp ? Wv2 : Wv1;  const float* bv = inp ? bv2 : bv1;

    const int lane = threadIdx.x & 63;
    const int w    = threadIdx.x >> 6;
    const int l15  = lane & 15, quad = lane >> 4;
    const int n0   = ntile * 32;

    f32x4 acc[7][2];
#pragma unroll
    for (int i = 0; i < 7; ++i)
#pragma unroll
        for (int j = 0; j < 2; ++j) acc[i][j] = (f32x4){0.f, 0.f, 0.f, 0.f};

    for (int kk = 0; kk < 8; ++kk) {
        const int ci0 = kk * 32 + quad * 8;
        bf16x8 bfr[2];
#pragma unroll
        for (int ns = 0; ns < 2; ++ns) {
            const int n = n0 + ns * 16 + l15;
            const float* xp = X + (size_t)ci0 * HW + n;
            float xv[8];
#pragma unroll
            for (int j = 0; j < 8; ++j) xv[j] = xp[(size_t)j * HW];
            union { bf16x8 v; unsigned u[4]; } t;
#pragma unroll
            for (int j = 0; j < 4; ++j) t.u[j] = pk2(xv[2*j+1], xv[2*j]);
            bfr[ns] = t.v;
        }
#pragma unroll
        for (int os = 0; os < 7; ++os) {
            const int osub = w * 7 + os;
            const int o    = osub * 16 + l15;      // A-frag row = lane&15
            const float* wrow;
            if (osub < 4)       wrow = Wq + (size_t)o * CDIM;
            else if (osub < 12) wrow = Wk + (size_t)(o - 64) * CDIM;
            else                wrow = Wv + (size_t)(o - 192) * CDIM;
            const float4 w0 = *(const float4*)(wrow + ci0);
            const float4 w1 = *(const float4*)(wrow + ci0 + 4);
            union { bf16x8 v; unsigned u[4]; } t;
            t.u[0] = pk2(w0.y, w0.x); t.u[1] = pk2(w0.w, w0.z);
            t.u[2] = pk2(w1.y, w1.x); t.u[3] = pk2(w1.w, w1.z);
#pragma unroll
            for (int ns = 0; ns < 2; ++ns)
                acc[os][ns] = __builtin_amdgcn_mfma_f32_16x16x32_bf16(t.v, bfr[ns], acc[os][ns], 0, 0, 0);
        }
    }

    const size_t qbase = (size_t)b * HW * 128;
    const size_t kbase = (size_t)(b * 2 + inp) * HW * 128;
    const size_t vbase = (size_t)(b * 2 + inp) * (size_t)CDIM * HW;
#pragma unroll
    for (int os = 0; os < 7; ++os) {
        const int osub = w * 7 + os;
#pragma unroll
        for (int ns = 0; ns < 2; ++ns) {
            const int n = n0 + ns * 16 + l15;      // D col = lane&15
            f32x4 d = acc[os][ns];
#pragma unroll
            for (int r = 0; r < 4; ++r) {
                const int o = osub * 16 + quad * 4 + r;   // D row = quad*4+reg
                if (osub < 4) {
                    Qg[qbase + (size_t)n * 128 + 2 * o + inp] = f2bf(d[r] + bq[o]);
                } else if (osub < 12) {
                    const int c = o - 64;
                    Kg[kbase + (size_t)n * 128 + c] = f2bf(d[r] + bk[c]);
                } else {
                    const int c = o - 192;
                    Vg[vbase + (size_t)c * HW + n] = f2bf(d[r] + bv[c]);
                }
            }
        }
    }
}

// ---------------------------------------------------------------------------
// Kernel 2: streaming attention, no max-subtraction (scores |s| <~ 6).
// grid 512: set = bid&3 (att,b) -> XCD-grouped; qt = bid>>2 (128 tiles of 32 n).
// 4 waves. S phase: wave = (nh = w>>1) x (mh = w&1) quadrant of 32x32.
// PV phase: wave = c-quarter (w*64..), all 32 n rows.
// Double-buffered async K/V staging (XOR-swizzled, conflict-free), 2 barriers/iter.
// ---------------------------------------------------------------------------
__global__ __launch_bounds__(256) void attn_kernel(
    const unsigned short* __restrict__ Qg, const unsigned short* __restrict__ Kg,
    const unsigned short* __restrict__ Vg,
    const float* __restrict__ in1, const float* __restrict__ in2,
    const float* __restrict__ gamma_p, float* __restrict__ out)
{
    __shared__ unsigned short kbuf[2][32 * 128];   // [m][c-chunk swizzled], 16 KB
    __shared__ unsigned short vbuf[2][256 * 32];   // [c][m-chunk swizzled], 32 KB
    __shared__ unsigned short pbuf[32 * 40];       // [n][m] pad 32->40
    __shared__ float lbuf[2][32];

    const int bid = blockIdx.x;
    const int att = bid & 1, b = (bid >> 1) & 1, qt = bid >> 2;
    const int n0g = qt * 32;
    const int tid = threadIdx.x;
    const int lane = tid & 63, w = tid >> 6;
    const int l15 = lane & 15, quad = lane >> 4;
    const int nh = w >> 1, mh = w & 1;

    const unsigned short* Qb = Qg + (size_t)b * HW * 128;
    const unsigned short* Kb = Kg + (size_t)(b * 2 + att) * HW * 128;
    const unsigned short* Vb = Vg + (size_t)(b * 2 + att) * (size_t)CDIM * HW;

    // Q A-frags for this wave's S rows: A[n=lane&15][k=quad*8+j]
    bf16x8 aQ[4];
    {
        const int nq = n0g + nh * 16 + l15;
#pragma unroll
        for (int kk = 0; kk < 4; ++kk)
            aQ[kk] = *(const bf16x8*)(Qb + (size_t)nq * 128 + kk * 32 + quad * 8);
    }

    f32x4 O[2][4];
#pragma unroll
    for (int i = 0; i < 2; ++i)
#pragma unroll
        for (int j = 0; j < 4; ++j) O[i][j] = (f32x4){0.f, 0.f, 0.f, 0.f};
    f32x4 lsum = (f32x4){0.f, 0.f, 0.f, 0.f};

    auto stage = [&](int mt2, int bsel) {
        const int m0 = mt2 * 32;
        // K tile: 32 rows x 16 chunks of 16B; lane's LDS slot (ml,cc) gets
        // global chunk cc^(ml&15)  -> reader at (mloc, jj^(mloc&15)) is conflict-free
#pragma unroll
        for (int t = 0; t < 2; ++t) {
            const int gchunk = (w * 2 + t) * 64 + lane;
            const int ml = gchunk >> 4, cc = gchunk & 15;
            const int ccg = cc ^ (ml & 15);
            gl_lds16(Kb + (size_t)(m0 + ml) * 128 + ccg * 8,
                     &kbuf[bsel][(w * 2 + t) * 512]);
        }
        // V tile: 256 rows x 4 chunks; slot (c,cc) gets global chunk cc^((c>>1)&3)
#pragma unroll
        for (int t = 0; t < 4; ++t) {
            const int gchunk = (w * 4 + t) * 64 + lane;
            const int c = gchunk >> 2, cc = gchunk & 3;
            const int ccg = cc ^ ((c >> 1) & 3);
            gl_lds16(Vb + (size_t)c * HW + m0 + ccg * 8,
                     &vbuf[bsel][(w * 4 + t) * 512]);
        }
    };

    stage(0, 0);
    __syncthreads();   // compiler emits vmcnt(0) drain before barrier

    const int mloc = mh * 16 + l15;
    for (int mt = 0; mt < 128; ++mt) {
        const int cur = mt & 1;
        if (mt + 1 < 128) stage(mt + 1, cur ^ 1);   // async into other buffer

        // S quadrant [16n x 16m]
        f32x4 s = (f32x4){0.f, 0.f, 0.f, 0.f};
#pragma unroll
        for (int kk = 0; kk < 4; ++kk) {
            bf16x8 bK = *(const bf16x8*)&kbuf[cur][mloc * 128 + ((kk * 4 + quad) ^ l15) * 8];
            s = __builtin_amdgcn_mfma_f32_16x16x32_bf16(aQ[kk], bK, s, 0, 0, 0);
        }
        f32x4 p;
#pragma unroll
        for (int r = 0; r < 4; ++r) p[r] = __expf(s[r]);
        lsum += p;
#pragma unroll
        for (int r = 0; r < 4; ++r)
            pbuf[(nh * 16 + quad * 4 + r) * 40 + mh * 16 + l15] = f2bf(p[r]);
        __syncthreads();   // drains next-tile loads; pbuf visible

        // PV: this wave does all 32 n x 64 c (quarter of channels)
        bf16x8 aP0 = *(const bf16x8*)&pbuf[(size_t)l15 * 40 + quad * 8];
        bf16x8 aP1 = *(const bf16x8*)&pbuf[(size_t)(16 + l15) * 40 + quad * 8];
#pragma unroll
        for (int cs = 0; cs < 4; ++cs) {
            const int c = w * 64 + cs * 16 + l15;
            bf16x8 bV = *(const bf16x8*)&vbuf[cur][c * 32 + (quad ^ ((c >> 1) & 3)) * 8];
            O[0][cs] = __builtin_amdgcn_mfma_f32_16x16x32_bf16(aP0, bV, O[0][cs], 0, 0, 0);
            O[1][cs] = __builtin_amdgcn_mfma_f32_16x16x32_bf16(aP1, bV, O[1][cs], 0, 0, 0);
        }
        __syncthreads();   // protect buffers from next iter's staging
    }

    // row-sum l: reduce over the 16 lanes of each quad, combine m-halves in LDS
#pragma unroll
    for (int off = 1; off < 16; off <<= 1)
#pragma unroll
        for (int r = 0; r < 4; ++r) lsum[r] += __shfl_xor(lsum[r], off, 64);
    if (l15 == 0) *(f32x4*)&lbuf[mh][nh * 16 + quad * 4] = lsum;
    __syncthreads();

    const float* inp  = (att ? in2 : in1) + (size_t)b * CDIM * HW;
    float*       outp = out + (size_t)att * 2 * CDIM * HW + (size_t)b * CDIM * HW;
    const float  g    = *gamma_p;
#pragma unroll
    for (int ns = 0; ns < 2; ++ns) {
        const int nb = ns * 16 + quad * 4;
        f32x4 l0 = *(const f32x4*)&lbuf[0][nb];
        f32x4 l1 = *(const f32x4*)&lbuf[1][nb];
        f32x4 linv;
#pragma unroll
        for (int r = 0; r < 4; ++r) linv[r] = 1.0f / (l0[r] + l1[r]);
#pragma unroll
        for (int cs = 0; cs < 4; ++cs) {
            const int c = w * 64 + cs * 16 + l15;
            const size_t base = (size_t)c * HW + n0g + nb;
#pragma unroll
            for (int r = 0; r < 4; ++r)
                outp[base + r] = g * O[ns][cs][r] * linv[r] + inp[base + r];
        }
    }
}

extern "C" void kernel_launch(void* const* d_in, const int* in_sizes, int n_in,
                              void* d_out, int out_size, void* d_ws, size_t ws_size,
                              hipStream_t stream) {
    const float* in1 = (const float*)d_in[0];
    const float* in2 = (const float*)d_in[1];
    const float* Wq1 = (const float*)d_in[2];  const float* bq1 = (const float*)d_in[3];
    const float* Wk1 = (const float*)d_in[4];  const float* bk1 = (const float*)d_in[5];
    const float* Wv1 = (const float*)d_in[6];  const float* bv1 = (const float*)d_in[7];
    const float* Wq2 = (const float*)d_in[8];  const float* bq2 = (const float*)d_in[9];
    const float* Wk2 = (const float*)d_in[10]; const float* bk2 = (const float*)d_in[11];
    const float* Wv2 = (const float*)d_in[12]; const float* bv2 = (const float*)d_in[13];
    const float* gamma = (const float*)d_in[14];

    unsigned short* Qg = (unsigned short*)d_ws;                 // [2][4096][128]
    unsigned short* Kg = Qg + (size_t)2 * HW * 128;             // [4][4096 m][128 c]
    unsigned short* Vg = Kg + (size_t)4 * HW * 128;             // [4][256 c][4096 m]

    proj_kernel<<<512, 256, 0, stream>>>(in1, in2, Wq1, bq1, Wk1, bk1, Wv1, bv1,
                                         Wq2, bq2, Wk2, bk2, Wv2, bv2, Qg, Kg, Vg);
    attn_kernel<<<512, 256, 0, stream>>>(Qg, Kg, Vg, in1, in2, gamma, (float*)d_out);
}